// Round 8
// baseline (274.458 us; speedup 1.0000x reference)
//
#include <hip/hip_runtime.h>

// ---------------------------------------------------------------------------
// GAT GNN: h0 = relu(GAT0(x)); h1 = relu(GAT1(h0));
// out = [x@We+be  ||  h1@Wn+bn]
// R3: bf16 features + MFMA GEMMs.  R4: low-contention 2-phase CSR build.
// R5: att fused into GEMM epilogue.  R6: split-lane agg.  R7: merged scan.
// R8: LDS-aware co-scheduling — scat1 paired with LDS-free prep (restores
//     32 waves/CU for the atomic phase; R7 paired it with the 52KB-LDS GEMM
//     and throttled it to 12 waves). gemm0+proj_ego+scat2 share one dispatch
//     with a pointer-carved common LDS pool (52KB, not 87KB).
// ---------------------------------------------------------------------------

#define LEAKY_SLOPE 0.2f

typedef __attribute__((ext_vector_type(8))) short s16x8;
typedef __attribute__((ext_vector_type(4))) float f32x4;

static __device__ __forceinline__ unsigned short f2bf(float f)
{
    unsigned x = __float_as_uint(f);
    unsigned r = (x + 0x7fffu + ((x >> 16) & 1u)) >> 16;   // RNE
    return (unsigned short)r;
}
static __device__ __forceinline__ float bfhi(unsigned u) { return __uint_as_float(u & 0xffff0000u); }
static __device__ __forceinline__ float bflo(unsigned u) { return __uint_as_float(u << 16); }

// ---------------- D1: zero cursors + done counter --------------------------
__global__ __launch_bounds__(256) void zero_k(int* __restrict__ p, int n)
{
    int i = blockIdx.x * 256 + threadIdx.x;
    if (i < n) p[i] = 0;
}

// ---------------- D2: [cast+pack || scat1] — both LDS-free -----------------
__global__ __launch_bounds__(256) void prep_scat1_k(const float* __restrict__ x,
                                                    const float* __restrict__ W0,
                                                    const float* __restrict__ W1,
                                                    const float* __restrict__ Wn,
                                                    const float* __restrict__ We,
                                                    unsigned short* __restrict__ xb,
                                                    unsigned short* __restrict__ P0,
                                                    unsigned short* __restrict__ P1,
                                                    unsigned short* __restrict__ Pn,
                                                    unsigned short* __restrict__ Pe,
                                                    const int* __restrict__ ei,
                                                    int* __restrict__ cursP,
                                                    int* __restrict__ slot,
                                                    int E, int n, int prepBlocks)
{
    if ((int)blockIdx.x < prepBlocks) {
        int gid = blockIdx.x * 256 + threadIdx.x;
        int nc = n * 32;                       // float4 count of x
        if (gid < nc) {
            float4 v = ((const float4*)x)[gid];
            ushort4 o;
            o.x = f2bf(v.x); o.y = f2bf(v.y); o.z = f2bf(v.z); o.w = f2bf(v.w);
            ((ushort4*)xb)[gid] = o;
        } else if (gid < nc + 49152) {
            int idx = gid - nc;
            const float* S; unsigned short* D; int BN; int local;
            if (idx < 16384)      { S = W0; D = P0; BN = 128; local = idx; }
            else if (idx < 32768) { S = W1; D = P1; BN = 128; local = idx - 16384; }
            else if (idx < 40960) { S = Wn; D = Pn; BN = 64;  local = idx - 32768; }
            else                  { S = We; D = Pe; BN = 64;  local = idx - 40960; }
            int k = local / BN, nn = local % BN;
            D[(((k >> 3) * BN + nn) * 8) + (k & 7)] = f2bf(S[local]);
        }
    } else {
        int e = (blockIdx.x - prepBlocks) * 256 + threadIdx.x;
        if (e < E + n) {
            int d = (e < E) ? ei[E + e] : (e - E);   // self-loop dst = node id
            slot[e] = atomicAdd(&cursP[d << 4], 1);
        }
    }
}

// ---------------- MFMA GEMM body (BN=128, LDS pool passed in) --------------
// HATT=4: layer0 logits (per-head in-wave). HATT=1: layer1 (LDS combine).
// LDS use: As 18432B + Bs 33280B + smS/smD 1024B = 52736B.
template<int HATT>
static __device__ __forceinline__ void gemm128_body(int tile, char* ldsraw,
                                                    const unsigned short* __restrict__ Ab,
                                                    const unsigned short* __restrict__ Bp,
                                                    unsigned short* __restrict__ Cb,
                                                    const float* __restrict__ ats,
                                                    const float* __restrict__ atd,
                                                    float* __restrict__ a_s,
                                                    float* __restrict__ a_d, int n)
{
    constexpr int BN = 128;
    constexpr int APITCH = 144;
    constexpr int BPITCH = BN + 2;

    unsigned short* As = (unsigned short*)ldsraw;            // 64*144
    unsigned short* Bs = As + 64 * APITCH;                   // 16*130*8
    float* smS = (float*)(Bs + 16 * BPITCH * 8);             // 64*2
    float* smD = smS + 128;                                  // 64*2

    const int t  = threadIdx.x;
    const int rb = tile * 64;

#pragma unroll
    for (int i = 0; i < 4; ++i) {
        int q = t + i * 256;
        int r = q >> 4;
        int c = (q & 15) * 8;
        float4 v = make_float4(0.f, 0.f, 0.f, 0.f);
        int gr = rb + r;
        if (gr < n) v = *(const float4*)(Ab + (size_t)gr * 128 + c);
        *(float4*)(As + r * APITCH + c) = v;
    }
#pragma unroll
    for (int i = 0; i < 8; ++i) {
        int ge = t + i * 256;
        int o = ge / BN, nn = ge % BN;
        *(float4*)(Bs + ((size_t)o * BPITCH + nn) * 8) = *(const float4*)(Bp + (size_t)ge * 8);
    }
    __syncthreads();

    const int w = t >> 6, lane = t & 63;
    const int m = lane & 15, quad = lane >> 4;
    const int wc = w & 1, wr = w >> 1;
    const int row0 = wr * 32;
    const int col0 = wc * 64;

    f32x4 acc[2][4];
#pragma unroll
    for (int rt = 0; rt < 2; ++rt)
#pragma unroll
        for (int c = 0; c < 4; ++c) acc[rt][c] = (f32x4){0.f, 0.f, 0.f, 0.f};

    s16x8 a[2][4];
#pragma unroll
    for (int rt = 0; rt < 2; ++rt)
#pragma unroll
        for (int kk = 0; kk < 4; ++kk)
            a[rt][kk] = *(const s16x8*)(As + (row0 + rt * 16 + m) * APITCH + kk * 32 + quad * 8);

#pragma unroll
    for (int kk = 0; kk < 4; ++kk)
#pragma unroll
        for (int c = 0; c < 4; ++c) {
            s16x8 b = *(const s16x8*)(Bs + ((size_t)(kk * 4 + quad) * BPITCH + col0 + c * 16 + m) * 8);
#pragma unroll
            for (int rt = 0; rt < 2; ++rt)
                acc[rt][c] = __builtin_amdgcn_mfma_f32_16x16x32_bf16(a[rt][kk], b, acc[rt][c], 0, 0, 0);
        }

    // ---- C store (C/D layout: col=lane&15, row=quad*4+reg) ----
#pragma unroll
    for (int rt = 0; rt < 2; ++rt)
#pragma unroll
        for (int c = 0; c < 4; ++c)
#pragma unroll
            for (int r = 0; r < 4; ++r) {
                int row = rb + row0 + rt * 16 + quad * 4 + r;
                int colg = col0 + c * 16 + m;
                if (row < n) Cb[(size_t)row * 128 + colg] = f2bf(acc[rt][c][r]);
            }

    // ---- fused attention logits ----
    float atsv[4], atdv[4];
#pragma unroll
    for (int c = 0; c < 4; ++c) {
        atsv[c] = ats[col0 + c * 16 + m];
        atdv[c] = atd[col0 + c * 16 + m];
    }
    if (HATT == 4) {
#pragma unroll
        for (int rt = 0; rt < 2; ++rt)
#pragma unroll
            for (int r = 0; r < 4; ++r)
#pragma unroll
                for (int hb = 0; hb < 2; ++hb) {
                    float ps = acc[rt][2*hb][r] * atsv[2*hb] + acc[rt][2*hb+1][r] * atsv[2*hb+1];
                    float pd = acc[rt][2*hb][r] * atdv[2*hb] + acc[rt][2*hb+1][r] * atdv[2*hb+1];
#pragma unroll
                    for (int off = 1; off < 16; off <<= 1) {
                        ps += __shfl_xor(ps, off);
                        pd += __shfl_xor(pd, off);
                    }
                    int row = rb + row0 + rt * 16 + quad * 4 + r;
                    if (m == 0 && row < n) {
                        a_s[(size_t)row * 4 + 2*wc + hb] = ps;
                        a_d[(size_t)row * 4 + 2*wc + hb] = pd;
                    }
                }
    }
    if (HATT == 1) {
#pragma unroll
        for (int rt = 0; rt < 2; ++rt)
#pragma unroll
            for (int r = 0; r < 4; ++r) {
                float ps = 0.f, pd = 0.f;
#pragma unroll
                for (int c = 0; c < 4; ++c) {
                    ps = fmaf(acc[rt][c][r], atsv[c], ps);
                    pd = fmaf(acc[rt][c][r], atdv[c], pd);
                }
#pragma unroll
                for (int off = 1; off < 16; off <<= 1) {
                    ps += __shfl_xor(ps, off);
                    pd += __shfl_xor(pd, off);
                }
                int lrow = row0 + rt * 16 + quad * 4 + r;
                if (m == 0) { smS[lrow * 2 + wc] = ps; smD[lrow * 2 + wc] = pd; }
            }
        __syncthreads();
        if (t < 64) {
            int row = rb + t;
            if (row < n) {
                a_s[row] = smS[t * 2] + smS[t * 2 + 1];
                a_d[row] = smD[t * 2] + smD[t * 2 + 1];
            }
        }
    }
}

// ---------------- projection GEMM body (BN=64, LDS pool passed in) ---------
// LDS use: As 18432B + Bs 16896B = 35328B.
static __device__ __forceinline__ void proj64_body(int tile, char* ldsraw,
                                                   const unsigned short* __restrict__ Ab,
                                                   const unsigned short* __restrict__ Bp,
                                                   const float* __restrict__ bias,
                                                   float* __restrict__ Cf, int n)
{
    constexpr int BN = 64;
    constexpr int APITCH = 144;
    constexpr int BPITCH = BN + 2;

    unsigned short* As = (unsigned short*)ldsraw;            // 64*144
    unsigned short* Bs = As + 64 * APITCH;                   // 16*66*8

    const int t  = threadIdx.x;
    const int rb = tile * 64;

#pragma unroll
    for (int i = 0; i < 4; ++i) {
        int q = t + i * 256;
        int r = q >> 4;
        int c = (q & 15) * 8;
        float4 v = make_float4(0.f, 0.f, 0.f, 0.f);
        int gr = rb + r;
        if (gr < n) v = *(const float4*)(Ab + (size_t)gr * 128 + c);
        *(float4*)(As + r * APITCH + c) = v;
    }
#pragma unroll
    for (int i = 0; i < 4; ++i) {
        int ge = t + i * 256;
        int o = ge / BN, nn = ge % BN;
        *(float4*)(Bs + ((size_t)o * BPITCH + nn) * 8) = *(const float4*)(Bp + (size_t)ge * 8);
    }
    __syncthreads();

    const int w = t >> 6, lane = t & 63;
    const int m = lane & 15, quad = lane >> 4;
    const int row0 = w * 16;

    f32x4 acc[4];
#pragma unroll
    for (int c = 0; c < 4; ++c) acc[c] = (f32x4){0.f, 0.f, 0.f, 0.f};

    s16x8 a[4];
#pragma unroll
    for (int kk = 0; kk < 4; ++kk)
        a[kk] = *(const s16x8*)(As + (row0 + m) * APITCH + kk * 32 + quad * 8);

#pragma unroll
    for (int kk = 0; kk < 4; ++kk)
#pragma unroll
        for (int c = 0; c < 4; ++c) {
            s16x8 b = *(const s16x8*)(Bs + ((size_t)(kk * 4 + quad) * BPITCH + c * 16 + m) * 8);
            acc[c] = __builtin_amdgcn_mfma_f32_16x16x32_bf16(a[kk], b, acc[c], 0, 0, 0);
        }

#pragma unroll
    for (int c = 0; c < 4; ++c)
#pragma unroll
        for (int r = 0; r < 4; ++r) {
            int row = rb + row0 + quad * 4 + r;
            int colg = c * 16 + m;
            if (row < n) Cf[(size_t)row * BN + colg] = acc[c][r] + bias[colg];
        }
}

// ---------------- D3: two-level exclusive scan, one dispatch ---------------
__global__ __launch_bounds__(256) void scanAB_k(const int* __restrict__ cursP,
                                                int* __restrict__ rowe,
                                                int* __restrict__ bsum,
                                                int* __restrict__ boff,
                                                int* __restrict__ done,
                                                int n, int nb)
{
    __shared__ int sm[256];
    __shared__ int flag;
    int t = threadIdx.x, i = blockIdx.x * 256 + t;
    int v = (i < n) ? cursP[i << 4] : 0;
    sm[t] = v;
    __syncthreads();
    for (int off = 1; off < 256; off <<= 1) {
        int x = (t >= off) ? sm[t - off] : 0;
        __syncthreads();
        sm[t] += x;
        __syncthreads();
    }
    if (i < n) rowe[i] = sm[t] - v;
    if (t == 255) {
        bsum[blockIdx.x] = sm[t];
        __threadfence();                 // publish bsum device-wide
    }
    __syncthreads();
    if (t == 0) {
        int old = atomicAdd(done, 1);
        flag = (old == nb - 1) ? 1 : 0;
    }
    __syncthreads();
    if (flag) {                          // last block: scan the block sums
        __threadfence();                 // acquire all blocks' bsum
        int v2 = (t < nb) ? bsum[t] : 0;
        sm[t] = v2;
        __syncthreads();
        for (int off = 1; off < 256; off <<= 1) {
            int x = (t >= off) ? sm[t - off] : 0;
            __syncthreads();
            sm[t] += x;
            __syncthreads();
        }
        if (t < nb) boff[t] = sm[t] - v2;
    }
}

// ---------------- D4: [gemm0+att0 || proj_ego || scat2] --------------------
__global__ __launch_bounds__(256) void gemm0_proj_scat2_k(
    const unsigned short* __restrict__ xb, const unsigned short* __restrict__ P0,
    unsigned short* __restrict__ xlb,
    const float* __restrict__ ats, const float* __restrict__ atd,
    float* __restrict__ a_s, float* __restrict__ a_d,
    const unsigned short* __restrict__ Pe, const float* __restrict__ be,
    float* __restrict__ outEgo,
    const int* __restrict__ ei, const int* __restrict__ rowe,
    const int* __restrict__ boff, const int* __restrict__ slot,
    int* __restrict__ col, int* __restrict__ rowf,
    int E, int n, int gN64)
{
    __shared__ __align__(16) char lds[52736];
    int b = blockIdx.x;
    if (b < gN64) {
        gemm128_body<4>(b, lds, xb, P0, xlb, ats, atd, a_s, a_d, n);
    } else if (b < 2 * gN64) {
        proj64_body(b - gN64, lds, xb, Pe, be, outEgo, n);
    } else {
        int e = (b - 2 * gN64) * 256 + threadIdx.x;
        int ET = E + n;
        if (e < ET) {
            int s = (e < E) ? ei[e]     : (e - E);
            int d = (e < E) ? ei[E + e] : (e - E);
            int base = rowe[d] + boff[d >> 8];
            col[base + slot[e]] = s;
        }
        if (e <= n) rowf[e] = (e < n) ? (rowe[e] + boff[e >> 8]) : ET;
    }
}

// ---------------- standalone gemm1 / proj_n --------------------------------
__global__ __launch_bounds__(256) void gemm1_k(const unsigned short* __restrict__ Ab,
                                               const unsigned short* __restrict__ Bp,
                                               unsigned short* __restrict__ Cb,
                                               const float* __restrict__ ats,
                                               const float* __restrict__ atd,
                                               float* __restrict__ a_s,
                                               float* __restrict__ a_d, int n)
{
    __shared__ __align__(16) char lds[52736];
    gemm128_body<1>(blockIdx.x, lds, Ab, Bp, Cb, ats, atd, a_s, a_d, n);
}

__global__ __launch_bounds__(256) void projN_k(const unsigned short* __restrict__ Ab,
                                               const unsigned short* __restrict__ Bp,
                                               const float* __restrict__ bias,
                                               float* __restrict__ Cf, int n)
{
    __shared__ __align__(16) char lds[35328];
    proj64_body(blockIdx.x, lds, Ab, Bp, bias, Cf, n);
}

// ---------------- GAT aggregation (split-lane, LDS-free) -------------------
template<int H>
__global__ __launch_bounds__(256) void agg_k(const unsigned short* __restrict__ xlb,
                                             const float* __restrict__ a_s,
                                             const float* __restrict__ a_d,
                                             const int* __restrict__ rowptr,
                                             const int* __restrict__ col,
                                             const float* __restrict__ bias,
                                             unsigned short* __restrict__ outb, int n)
{
    int node = (blockIdx.x * 256 + threadIdx.x) >> 6;
    int lane = threadIdx.x & 63;
    if (node >= n) return;
    const int sub = lane >> 5, sl = lane & 31;
    const int h = (H == 1) ? 0 : (sl >> 3);          // 4 ch/lane, C=32 per head
    float ad = a_d[(size_t)node * H + h];
    int p0 = rowptr[node], p1 = rowptr[node + 1];
    float a0 = 0.f, a1 = 0.f, a2 = 0.f, a3 = 0.f, den = 0.f;
    const unsigned short* xlj = xlb + 4 * sl;

    for (int base = p0; base < p1; base += 64) {
        int m = p1 - base;
        if (m > 64) m = 64;
        int cv = col[base + (lane < m ? lane : m - 1)];
        int j = 0;
        for (; j + 16 <= m; j += 16) {
            int jb = j + 8 * sub;
            int s[8]; float as[8]; uint2 uv[8];
#pragma unroll
            for (int q = 0; q < 8; ++q) s[q] = __shfl(cv, jb + q);
#pragma unroll
            for (int q = 0; q < 8; ++q) as[q] = a_s[(size_t)s[q] * H + h];
#pragma unroll
            for (int q = 0; q < 8; ++q) uv[q] = *(const uint2*)(xlj + (size_t)s[q] * 128);
#pragma unroll
            for (int q = 0; q < 8; ++q) {
                float al = as[q] + ad;
                al = (al >= 0.f) ? al : LEAKY_SLOPE * al;
                float w = __expf(al);
                a0 = fmaf(w, bflo(uv[q].x), a0);
                a1 = fmaf(w, bfhi(uv[q].x), a1);
                a2 = fmaf(w, bflo(uv[q].y), a2);
                a3 = fmaf(w, bfhi(uv[q].y), a3);
                den += w;
            }
        }
        int rem = m - j;
        if (rem > 0) {
            int cnt = sub ? (rem > 8 ? rem - 8 : 0) : (rem < 8 ? rem : 8);
            int jb = j + 8 * sub;
            int s[8]; float as[8]; uint2 uv[8];
#pragma unroll
            for (int q = 0; q < 8; ++q) s[q] = __shfl(cv, (q < cnt) ? (jb + q) : j);
#pragma unroll
            for (int q = 0; q < 8; ++q) as[q] = a_s[(size_t)s[q] * H + h];
#pragma unroll
            for (int q = 0; q < 8; ++q) uv[q] = *(const uint2*)(xlj + (size_t)s[q] * 128);
#pragma unroll
            for (int q = 0; q < 8; ++q) {
                float al = as[q] + ad;
                al = (al >= 0.f) ? al : LEAKY_SLOPE * al;
                float w = (q < cnt) ? __expf(al) : 0.f;
                a0 = fmaf(w, bflo(uv[q].x), a0);
                a1 = fmaf(w, bfhi(uv[q].x), a1);
                a2 = fmaf(w, bflo(uv[q].y), a2);
                a3 = fmaf(w, bfhi(uv[q].y), a3);
                den += w;
            }
        }
    }

    // combine sub-waves
    a0 += __shfl_xor(a0, 32);
    a1 += __shfl_xor(a1, 32);
    a2 += __shfl_xor(a2, 32);
    a3 += __shfl_xor(a3, 32);
    den += __shfl_xor(den, 32);

    if (sub == 0) {
        float inv = 1.0f / (den + 1e-16f);
        int j = 4 * sl;
        float o0 = fmaxf(fmaf(a0, inv, bias[j]),     0.f);
        float o1 = fmaxf(fmaf(a1, inv, bias[j + 1]), 0.f);
        float o2 = fmaxf(fmaf(a2, inv, bias[j + 2]), 0.f);
        float o3 = fmaxf(fmaf(a3, inv, bias[j + 3]), 0.f);
        uint2 pk;
        pk.x = (unsigned)f2bf(o0) | ((unsigned)f2bf(o1) << 16);
        pk.y = (unsigned)f2bf(o2) | ((unsigned)f2bf(o3) << 16);
        *(uint2*)(outb + (size_t)node * 128 + j) = pk;
    }
}

// ---------------------------------------------------------------------------
extern "C" void kernel_launch(void* const* d_in, const int* in_sizes, int n_in,
                              void* d_out, int out_size, void* d_ws, size_t ws_size,
                              hipStream_t stream)
{
    const float* x   = (const float*)d_in[0];
    const int*   ei  = (const int*)d_in[1];
    const float* W0  = (const float*)d_in[2];
    const float* as0 = (const float*)d_in[3];
    const float* ad0 = (const float*)d_in[4];
    const float* b0  = (const float*)d_in[5];
    const float* W1  = (const float*)d_in[6];
    const float* as1 = (const float*)d_in[7];
    const float* ad1 = (const float*)d_in[8];
    const float* b1  = (const float*)d_in[9];
    const float* Wn  = (const float*)d_in[10];
    const float* bn  = (const float*)d_in[11];
    const float* We  = (const float*)d_in[12];
    const float* be  = (const float*)d_in[13];

    const int n  = in_sizes[0] / 128;
    const int E  = in_sizes[1] / 2;
    const int ET = E + n;
    float* out = (float*)d_out;

    char* w = (char*)d_ws;
    auto carve = [&](size_t bytes) -> void* {
        void* p = (void*)w;
        w += (bytes + 255) & ~(size_t)255;
        return p;
    };
    unsigned short* xb  = (unsigned short*)carve((size_t)n * 128 * 2);
    unsigned short* xlb = (unsigned short*)carve((size_t)n * 128 * 2);
    unsigned short* hb  = (unsigned short*)carve((size_t)n * 128 * 2);
    float* a_s  = (float*)carve((size_t)n * 4 * 4);
    float* a_d  = (float*)carve((size_t)n * 4 * 4);
    int*   curs = (int*)carve((size_t)(n * 16 + 16) * 4);  // padded cursors + done
    int*   rowe = (int*)carve((size_t)n * 4);              // block-local excl scan
    int*   rowf = (int*)carve((size_t)(n + 1) * 4);        // final rowptr
    int*   slot = (int*)carve((size_t)ET * 4);
    int*   colv = (int*)carve((size_t)ET * 4);
    int*   bsum = (int*)carve(1024);
    int*   boff = (int*)carve(1024);
    unsigned short* P0 = (unsigned short*)carve(16384 * 2);
    unsigned short* P1 = (unsigned short*)carve(16384 * 2);
    unsigned short* Pn = (unsigned short*)carve(8192 * 2);
    unsigned short* Pe = (unsigned short*)carve(8192 * 2);
    int* done = curs + (size_t)n * 16;

    const int gN64 = (n + 63) / 64;
    const int gWv  = (n + 3) / 4;
    const int gE   = (ET + 255) / 256;
    const int NB   = (n + 255) / 256;     // must be <= 256

    // ---- D1: zero cursors + done ----
    const int zn = n * 16 + 16;
    zero_k<<<(zn + 255) / 256, 256, 0, stream>>>(curs, zn);

    // ---- D2: [cast+pack || scat1] (both LDS-free, full occupancy) ----
    const int prepBlocks = (n * 32 + 49152 + 255) / 256;
    prep_scat1_k<<<prepBlocks + gE, 256, 0, stream>>>(x, W0, W1, Wn, We,
                                                      xb, P0, P1, Pn, Pe,
                                                      ei, curs, slot, E, n, prepBlocks);

    // ---- D3: two-level scan (one dispatch) ----
    scanAB_k<<<NB, 256, 0, stream>>>(curs, rowe, bsum, boff, done, n, NB);

    // ---- D4: [gemm0+att0 || proj_ego || scat2] ----
    gemm0_proj_scat2_k<<<2 * gN64 + gE, 256, 0, stream>>>(xb, P0, xlb, as0, ad0, a_s, a_d,
                                                          Pe, be, out,
                                                          ei, rowe, boff, slot, colv, rowf,
                                                          E, n, gN64);

    // ---- D5: layer-0 aggregation ----
    agg_k<4><<<gWv, 256, 0, stream>>>(xlb, a_s, a_d, rowf, colv, b0, hb, n);

    // ---- D6: gemm1 + att1 ----
    gemm1_k<<<gN64, 256, 0, stream>>>(hb, P1, xlb, as1, ad1, a_s, a_d, n);

    // ---- D7: layer-1 aggregation ----
    agg_k<1><<<gWv, 256, 0, stream>>>(xlb, a_s, a_d, rowf, colv, b1, hb, n);

    // ---- D8: h_neighbor projection ----
    projN_k<<<gN64, 256, 0, stream>>>(hb, Pn, bn, out + (size_t)n * 64, n);
}

// Round 9
// 274.296 us; speedup vs baseline: 1.0006x; 1.0006x over previous
//
#include <hip/hip_runtime.h>

// ---------------------------------------------------------------------------
// GAT GNN: h0 = relu(GAT0(x)); h1 = relu(GAT1(h0));
// out = [x@We+be  ||  h1@Wn+bn]
// R3: bf16 features + MFMA GEMMs.  R4: low-contention 2-phase CSR build.
// R5: att fused into GEMM epilogue.  R7: merged scan.
// R9: agg_k -> 16 lanes/edge dwordx4 gathers (4 edges per 1KB wave-instr,
//     halves VMEM issue count; R6 showed the kernel is issue-rate-bound);
//     scat1 blocks FIRST in the prep co-schedule (R8 had them last -> serial);
//     scat2 standalone (R8 had it LDS-capped inside the MFMA kernel).
// ---------------------------------------------------------------------------

#define LEAKY_SLOPE 0.2f

typedef __attribute__((ext_vector_type(8))) short s16x8;
typedef __attribute__((ext_vector_type(4))) float f32x4;

static __device__ __forceinline__ unsigned short f2bf(float f)
{
    unsigned x = __float_as_uint(f);
    unsigned r = (x + 0x7fffu + ((x >> 16) & 1u)) >> 16;   // RNE
    return (unsigned short)r;
}
static __device__ __forceinline__ float bfhi(unsigned u) { return __uint_as_float(u & 0xffff0000u); }
static __device__ __forceinline__ float bflo(unsigned u) { return __uint_as_float(u << 16); }

// ---------------- D1: zero cursors + done counter --------------------------
__global__ __launch_bounds__(256) void zero_k(int* __restrict__ p, int n)
{
    int i = blockIdx.x * 256 + threadIdx.x;
    if (i < n) p[i] = 0;
}

// ---------------- D2: [scat1 (first!) || cast+pack] — both LDS-free --------
__global__ __launch_bounds__(256) void scat1_prep_k(const int* __restrict__ ei,
                                                    int* __restrict__ cursP,
                                                    int* __restrict__ slot,
                                                    const float* __restrict__ x,
                                                    const float* __restrict__ W0,
                                                    const float* __restrict__ W1,
                                                    const float* __restrict__ Wn,
                                                    const float* __restrict__ We,
                                                    unsigned short* __restrict__ xb,
                                                    unsigned short* __restrict__ P0,
                                                    unsigned short* __restrict__ P1,
                                                    unsigned short* __restrict__ Pn,
                                                    unsigned short* __restrict__ Pe,
                                                    int E, int n, int scatBlocks)
{
    if ((int)blockIdx.x < scatBlocks) {
        int e = blockIdx.x * 256 + threadIdx.x;
        if (e < E + n) {
            int d = (e < E) ? ei[E + e] : (e - E);   // self-loop dst = node id
            slot[e] = atomicAdd(&cursP[d << 4], 1);
        }
    } else {
        int gid = (blockIdx.x - scatBlocks) * 256 + threadIdx.x;
        int nc = n * 32;                       // float4 count of x
        if (gid < nc) {
            float4 v = ((const float4*)x)[gid];
            ushort4 o;
            o.x = f2bf(v.x); o.y = f2bf(v.y); o.z = f2bf(v.z); o.w = f2bf(v.w);
            ((ushort4*)xb)[gid] = o;
        } else if (gid < nc + 49152) {
            int idx = gid - nc;
            const float* S; unsigned short* D; int BN; int local;
            if (idx < 16384)      { S = W0; D = P0; BN = 128; local = idx; }
            else if (idx < 32768) { S = W1; D = P1; BN = 128; local = idx - 16384; }
            else if (idx < 40960) { S = Wn; D = Pn; BN = 64;  local = idx - 32768; }
            else                  { S = We; D = Pe; BN = 64;  local = idx - 40960; }
            int k = local / BN, nn = local % BN;
            D[(((k >> 3) * BN + nn) * 8) + (k & 7)] = f2bf(S[local]);
        }
    }
}

// ---------------- MFMA GEMM body (BN=128, LDS pool passed in) --------------
// HATT=4: layer0 logits (per-head in-wave). HATT=1: layer1 (LDS combine).
// LDS use: As 18432B + Bs 33280B + smS/smD 1024B = 52736B.
template<int HATT>
static __device__ __forceinline__ void gemm128_body(int tile, char* ldsraw,
                                                    const unsigned short* __restrict__ Ab,
                                                    const unsigned short* __restrict__ Bp,
                                                    unsigned short* __restrict__ Cb,
                                                    const float* __restrict__ ats,
                                                    const float* __restrict__ atd,
                                                    float* __restrict__ a_s,
                                                    float* __restrict__ a_d, int n)
{
    constexpr int BN = 128;
    constexpr int APITCH = 144;
    constexpr int BPITCH = BN + 2;

    unsigned short* As = (unsigned short*)ldsraw;            // 64*144
    unsigned short* Bs = As + 64 * APITCH;                   // 16*130*8
    float* smS = (float*)(Bs + 16 * BPITCH * 8);             // 64*2
    float* smD = smS + 128;                                  // 64*2

    const int t  = threadIdx.x;
    const int rb = tile * 64;

#pragma unroll
    for (int i = 0; i < 4; ++i) {
        int q = t + i * 256;
        int r = q >> 4;
        int c = (q & 15) * 8;
        float4 v = make_float4(0.f, 0.f, 0.f, 0.f);
        int gr = rb + r;
        if (gr < n) v = *(const float4*)(Ab + (size_t)gr * 128 + c);
        *(float4*)(As + r * APITCH + c) = v;
    }
#pragma unroll
    for (int i = 0; i < 8; ++i) {
        int ge = t + i * 256;
        int o = ge / BN, nn = ge % BN;
        *(float4*)(Bs + ((size_t)o * BPITCH + nn) * 8) = *(const float4*)(Bp + (size_t)ge * 8);
    }
    __syncthreads();

    const int w = t >> 6, lane = t & 63;
    const int m = lane & 15, quad = lane >> 4;
    const int wc = w & 1, wr = w >> 1;
    const int row0 = wr * 32;
    const int col0 = wc * 64;

    f32x4 acc[2][4];
#pragma unroll
    for (int rt = 0; rt < 2; ++rt)
#pragma unroll
        for (int c = 0; c < 4; ++c) acc[rt][c] = (f32x4){0.f, 0.f, 0.f, 0.f};

    s16x8 a[2][4];
#pragma unroll
    for (int rt = 0; rt < 2; ++rt)
#pragma unroll
        for (int kk = 0; kk < 4; ++kk)
            a[rt][kk] = *(const s16x8*)(As + (row0 + rt * 16 + m) * APITCH + kk * 32 + quad * 8);

#pragma unroll
    for (int kk = 0; kk < 4; ++kk)
#pragma unroll
        for (int c = 0; c < 4; ++c) {
            s16x8 b = *(const s16x8*)(Bs + ((size_t)(kk * 4 + quad) * BPITCH + col0 + c * 16 + m) * 8);
#pragma unroll
            for (int rt = 0; rt < 2; ++rt)
                acc[rt][c] = __builtin_amdgcn_mfma_f32_16x16x32_bf16(a[rt][kk], b, acc[rt][c], 0, 0, 0);
        }

    // ---- C store (C/D layout: col=lane&15, row=quad*4+reg) ----
#pragma unroll
    for (int rt = 0; rt < 2; ++rt)
#pragma unroll
        for (int c = 0; c < 4; ++c)
#pragma unroll
            for (int r = 0; r < 4; ++r) {
                int row = rb + row0 + rt * 16 + quad * 4 + r;
                int colg = col0 + c * 16 + m;
                if (row < n) Cb[(size_t)row * 128 + colg] = f2bf(acc[rt][c][r]);
            }

    // ---- fused attention logits ----
    float atsv[4], atdv[4];
#pragma unroll
    for (int c = 0; c < 4; ++c) {
        atsv[c] = ats[col0 + c * 16 + m];
        atdv[c] = atd[col0 + c * 16 + m];
    }
    if (HATT == 4) {
#pragma unroll
        for (int rt = 0; rt < 2; ++rt)
#pragma unroll
            for (int r = 0; r < 4; ++r)
#pragma unroll
                for (int hb = 0; hb < 2; ++hb) {
                    float ps = acc[rt][2*hb][r] * atsv[2*hb] + acc[rt][2*hb+1][r] * atsv[2*hb+1];
                    float pd = acc[rt][2*hb][r] * atdv[2*hb] + acc[rt][2*hb+1][r] * atdv[2*hb+1];
#pragma unroll
                    for (int off = 1; off < 16; off <<= 1) {
                        ps += __shfl_xor(ps, off);
                        pd += __shfl_xor(pd, off);
                    }
                    int row = rb + row0 + rt * 16 + quad * 4 + r;
                    if (m == 0 && row < n) {
                        a_s[(size_t)row * 4 + 2*wc + hb] = ps;
                        a_d[(size_t)row * 4 + 2*wc + hb] = pd;
                    }
                }
    }
    if (HATT == 1) {
#pragma unroll
        for (int rt = 0; rt < 2; ++rt)
#pragma unroll
            for (int r = 0; r < 4; ++r) {
                float ps = 0.f, pd = 0.f;
#pragma unroll
                for (int c = 0; c < 4; ++c) {
                    ps = fmaf(acc[rt][c][r], atsv[c], ps);
                    pd = fmaf(acc[rt][c][r], atdv[c], pd);
                }
#pragma unroll
                for (int off = 1; off < 16; off <<= 1) {
                    ps += __shfl_xor(ps, off);
                    pd += __shfl_xor(pd, off);
                }
                int lrow = row0 + rt * 16 + quad * 4 + r;
                if (m == 0) { smS[lrow * 2 + wc] = ps; smD[lrow * 2 + wc] = pd; }
            }
        __syncthreads();
        if (t < 64) {
            int row = rb + t;
            if (row < n) {
                a_s[row] = smS[t * 2] + smS[t * 2 + 1];
                a_d[row] = smD[t * 2] + smD[t * 2 + 1];
            }
        }
    }
}

// ---------------- projection GEMM body (BN=64, LDS pool passed in) ---------
static __device__ __forceinline__ void proj64_body(int tile, char* ldsraw,
                                                   const unsigned short* __restrict__ Ab,
                                                   const unsigned short* __restrict__ Bp,
                                                   const float* __restrict__ bias,
                                                   float* __restrict__ Cf, int n)
{
    constexpr int BN = 64;
    constexpr int APITCH = 144;
    constexpr int BPITCH = BN + 2;

    unsigned short* As = (unsigned short*)ldsraw;            // 64*144
    unsigned short* Bs = As + 64 * APITCH;                   // 16*66*8

    const int t  = threadIdx.x;
    const int rb = tile * 64;

#pragma unroll
    for (int i = 0; i < 4; ++i) {
        int q = t + i * 256;
        int r = q >> 4;
        int c = (q & 15) * 8;
        float4 v = make_float4(0.f, 0.f, 0.f, 0.f);
        int gr = rb + r;
        if (gr < n) v = *(const float4*)(Ab + (size_t)gr * 128 + c);
        *(float4*)(As + r * APITCH + c) = v;
    }
#pragma unroll
    for (int i = 0; i < 4; ++i) {
        int ge = t + i * 256;
        int o = ge / BN, nn = ge % BN;
        *(float4*)(Bs + ((size_t)o * BPITCH + nn) * 8) = *(const float4*)(Bp + (size_t)ge * 8);
    }
    __syncthreads();

    const int w = t >> 6, lane = t & 63;
    const int m = lane & 15, quad = lane >> 4;
    const int row0 = w * 16;

    f32x4 acc[4];
#pragma unroll
    for (int c = 0; c < 4; ++c) acc[c] = (f32x4){0.f, 0.f, 0.f, 0.f};

    s16x8 a[4];
#pragma unroll
    for (int kk = 0; kk < 4; ++kk)
        a[kk] = *(const s16x8*)(As + (row0 + m) * APITCH + kk * 32 + quad * 8);

#pragma unroll
    for (int kk = 0; kk < 4; ++kk)
#pragma unroll
        for (int c = 0; c < 4; ++c) {
            s16x8 b = *(const s16x8*)(Bs + ((size_t)(kk * 4 + quad) * BPITCH + c * 16 + m) * 8);
            acc[c] = __builtin_amdgcn_mfma_f32_16x16x32_bf16(a[kk], b, acc[c], 0, 0, 0);
        }

#pragma unroll
    for (int c = 0; c < 4; ++c)
#pragma unroll
        for (int r = 0; r < 4; ++r) {
            int row = rb + row0 + quad * 4 + r;
            int colg = c * 16 + m;
            if (row < n) Cf[(size_t)row * BN + colg] = acc[c][r] + bias[colg];
        }
}

// ---------------- D3: two-level exclusive scan, one dispatch ---------------
__global__ __launch_bounds__(256) void scanAB_k(const int* __restrict__ cursP,
                                                int* __restrict__ rowe,
                                                int* __restrict__ bsum,
                                                int* __restrict__ boff,
                                                int* __restrict__ done,
                                                int n, int nb)
{
    __shared__ int sm[256];
    __shared__ int flag;
    int t = threadIdx.x, i = blockIdx.x * 256 + t;
    int v = (i < n) ? cursP[i << 4] : 0;
    sm[t] = v;
    __syncthreads();
    for (int off = 1; off < 256; off <<= 1) {
        int x = (t >= off) ? sm[t - off] : 0;
        __syncthreads();
        sm[t] += x;
        __syncthreads();
    }
    if (i < n) rowe[i] = sm[t] - v;
    if (t == 255) {
        bsum[blockIdx.x] = sm[t];
        __threadfence();                 // publish bsum device-wide
    }
    __syncthreads();
    if (t == 0) {
        int old = atomicAdd(done, 1);
        flag = (old == nb - 1) ? 1 : 0;
    }
    __syncthreads();
    if (flag) {                          // last block: scan the block sums
        __threadfence();                 // acquire all blocks' bsum
        int v2 = (t < nb) ? bsum[t] : 0;
        sm[t] = v2;
        __syncthreads();
        for (int off = 1; off < 256; off <<= 1) {
            int x = (t >= off) ? sm[t - off] : 0;
            __syncthreads();
            sm[t] += x;
            __syncthreads();
        }
        if (t < nb) boff[t] = sm[t] - v2;
    }
}

// ---------------- D4: scat2 standalone (atomic-free, LDS-free) -------------
__global__ __launch_bounds__(256) void scat2_k(const int* __restrict__ ei,
                                               const int* __restrict__ rowe,
                                               const int* __restrict__ boff,
                                               const int* __restrict__ slot,
                                               int* __restrict__ col,
                                               int* __restrict__ rowf,
                                               int E, int n)
{
    int e = blockIdx.x * 256 + threadIdx.x;
    int ET = E + n;
    if (e < ET) {
        int s = (e < E) ? ei[e]     : (e - E);
        int d = (e < E) ? ei[E + e] : (e - E);
        int base = rowe[d] + boff[d >> 8];
        col[base + slot[e]] = s;
    }
    if (e <= n) rowf[e] = (e < n) ? (rowe[e] + boff[e >> 8]) : ET;
}

// ---------------- D5: [gemm0+att0 || proj_ego] (shared 52KB LDS pool) ------
__global__ __launch_bounds__(256) void gemm0_proj_k(
    const unsigned short* __restrict__ xb, const unsigned short* __restrict__ P0,
    unsigned short* __restrict__ xlb,
    const float* __restrict__ ats, const float* __restrict__ atd,
    float* __restrict__ a_s, float* __restrict__ a_d,
    const unsigned short* __restrict__ Pe, const float* __restrict__ be,
    float* __restrict__ outEgo, int n, int gN64)
{
    __shared__ __align__(16) char lds[52736];
    int b = blockIdx.x;
    if (b < gN64) gemm128_body<4>(b, lds, xb, P0, xlb, ats, atd, a_s, a_d, n);
    else          proj64_body(b - gN64, lds, xb, Pe, be, outEgo, n);
}

// ---------------- standalone gemm1 / proj_n --------------------------------
__global__ __launch_bounds__(256) void gemm1_k(const unsigned short* __restrict__ Ab,
                                               const unsigned short* __restrict__ Bp,
                                               unsigned short* __restrict__ Cb,
                                               const float* __restrict__ ats,
                                               const float* __restrict__ atd,
                                               float* __restrict__ a_s,
                                               float* __restrict__ a_d, int n)
{
    __shared__ __align__(16) char lds[52736];
    gemm128_body<1>(blockIdx.x, lds, Ab, Bp, Cb, ats, atd, a_s, a_d, n);
}

__global__ __launch_bounds__(256) void projN_k(const unsigned short* __restrict__ Ab,
                                               const unsigned short* __restrict__ Bp,
                                               const float* __restrict__ bias,
                                               float* __restrict__ Cf, int n)
{
    __shared__ __align__(16) char lds[35328];
    proj64_body(blockIdx.x, lds, Ab, Bp, bias, Cf, n);
}

// ---------------- GAT aggregation (R9: 16 lanes/edge, dwordx4) -------------
// One wave per dst node. 4 sub-groups of 16 lanes; 8 ch/lane (dwordx4 = 16B).
// Edges interleaved mod-4 across subs -> wave-uniform batch count (no
// divergent shfl). Each 1KB wave-instruction gathers 4 edge rows. Masked
// lanes dup edge 0 (same-address, coalesced). Cross-sub combine: xor16+xor32.
template<int H>
__global__ __launch_bounds__(256) void agg_k(const unsigned short* __restrict__ xlb,
                                             const float* __restrict__ a_s,
                                             const float* __restrict__ a_d,
                                             const int* __restrict__ rowptr,
                                             const int* __restrict__ col,
                                             const float* __restrict__ bias,
                                             unsigned short* __restrict__ outb, int n)
{
    int node = (blockIdx.x * 256 + threadIdx.x) >> 6;
    int lane = threadIdx.x & 63;
    if (node >= n) return;
    const int sub = lane >> 4, sl = lane & 15;
    const int h = (H == 1) ? 0 : (sl >> 2);          // 8 ch/lane, C=32 per head
    float ad = a_d[(size_t)node * H + h];
    int p0 = rowptr[node], p1 = rowptr[node + 1];
    float acc[8];
#pragma unroll
    for (int i = 0; i < 8; ++i) acc[i] = 0.f;
    float den = 0.f;
    const unsigned short* xlj = xlb + 8 * sl;

    for (int base = p0; base < p1; base += 64) {
        int m = p1 - base;
        if (m > 64) m = 64;
        int cv = col[base + (lane < m ? lane : m - 1)];
        int nb = (m + 31) >> 5;                      // batches of 32 edges (8/sub)
        for (int kk = 0; kk < nb; ++kk) {
            int s[8]; float as[8]; uint4 uv[8]; bool val[8];
#pragma unroll
            for (int q = 0; q < 8; ++q) {
                int e = ((kk * 8 + q) << 2) + sub;   // interleaved mod-4
                val[q] = e < m;
                s[q] = __shfl(cv, val[q] ? e : 0);
            }
#pragma unroll
            for (int q = 0; q < 8; ++q) as[q] = a_s[(size_t)s[q] * H + h];
#pragma unroll
            for (int q = 0; q < 8; ++q) uv[q] = *(const uint4*)(xlj + (size_t)s[q] * 128);
#pragma unroll
            for (int q = 0; q < 8; ++q) {
                float al = as[q] + ad;
                al = (al >= 0.f) ? al : LEAKY_SLOPE * al;
                float w = val[q] ? __expf(al) : 0.f;
                den += w;
                acc[0] = fmaf(w, bflo(uv[q].x), acc[0]);
                acc[1] = fmaf(w, bfhi(uv[q].x), acc[1]);
                acc[2] = fmaf(w, bflo(uv[q].y), acc[2]);
                acc[3] = fmaf(w, bfhi(uv[q].y), acc[3]);
                acc[4] = fmaf(w, bflo(uv[q].z), acc[4]);
                acc[5] = fmaf(w, bfhi(uv[q].z), acc[5]);
                acc[6] = fmaf(w, bflo(uv[q].w), acc[6]);
                acc[7] = fmaf(w, bfhi(uv[q].w), acc[7]);
            }
        }
    }

    // combine the 4 sub-groups (each sub's 16 lanes hold identical den)
#pragma unroll
    for (int i = 0; i < 8; ++i) {
        acc[i] += __shfl_xor(acc[i], 16);
        acc[i] += __shfl_xor(acc[i], 32);
    }
    den += __shfl_xor(den, 16);
    den += __shfl_xor(den, 32);

    if (sub == 0) {
        float inv = 1.0f / (den + 1e-16f);
        int j = 8 * sl;
        unsigned pk[4];
#pragma unroll
        for (int i = 0; i < 4; ++i) {
            float o0 = fmaxf(fmaf(acc[2*i],     inv, bias[j + 2*i]),     0.f);
            float o1 = fmaxf(fmaf(acc[2*i + 1], inv, bias[j + 2*i + 1]), 0.f);
            pk[i] = (unsigned)f2bf(o0) | ((unsigned)f2bf(o1) << 16);
        }
        *(uint4*)(outb + (size_t)node * 128 + j) = make_uint4(pk[0], pk[1], pk[2], pk[3]);
    }
}

// ---------------------------------------------------------------------------
extern "C" void kernel_launch(void* const* d_in, const int* in_sizes, int n_in,
                              void* d_out, int out_size, void* d_ws, size_t ws_size,
                              hipStream_t stream)
{
    const float* x   = (const float*)d_in[0];
    const int*   ei  = (const int*)d_in[1];
    const float* W0  = (const float*)d_in[2];
    const float* as0 = (const float*)d_in[3];
    const float* ad0 = (const float*)d_in[4];
    const float* b0  = (const float*)d_in[5];
    const float* W1  = (const float*)d_in[6];
    const float* as1 = (const float*)d_in[7];
    const float* ad1 = (const float*)d_in[8];
    const float* b1  = (const float*)d_in[9];
    const float* Wn  = (const float*)d_in[10];
    const float* bn  = (const float*)d_in[11];
    const float* We  = (const float*)d_in[12];
    const float* be  = (const float*)d_in[13];

    const int n  = in_sizes[0] / 128;
    const int E  = in_sizes[1] / 2;
    const int ET = E + n;
    float* out = (float*)d_out;

    char* w = (char*)d_ws;
    auto carve = [&](size_t bytes) -> void* {
        void* p = (void*)w;
        w += (bytes + 255) & ~(size_t)255;
        return p;
    };
    unsigned short* xb  = (unsigned short*)carve((size_t)n * 128 * 2);
    unsigned short* xlb = (unsigned short*)carve((size_t)n * 128 * 2);
    unsigned short* hb  = (unsigned short*)carve((size_t)n * 128 * 2);
    float* a_s  = (float*)carve((size_t)n * 4 * 4);
    float* a_d  = (float*)carve((size_t)n * 4 * 4);
    int*   curs = (int*)carve((size_t)(n * 16 + 16) * 4);  // padded cursors + done
    int*   rowe = (int*)carve((size_t)n * 4);              // block-local excl scan
    int*   rowf = (int*)carve((size_t)(n + 1) * 4);        // final rowptr
    int*   slot = (int*)carve((size_t)ET * 4);
    int*   colv = (int*)carve((size_t)ET * 4);
    int*   bsum = (int*)carve(1024);
    int*   boff = (int*)carve(1024);
    unsigned short* P0 = (unsigned short*)carve(16384 * 2);
    unsigned short* P1 = (unsigned short*)carve(16384 * 2);
    unsigned short* Pn = (unsigned short*)carve(8192 * 2);
    unsigned short* Pe = (unsigned short*)carve(8192 * 2);
    int* done = curs + (size_t)n * 16;

    const int gN64 = (n + 63) / 64;
    const int gWv  = (n + 3) / 4;
    const int gE   = (ET + 255) / 256;
    const int NB   = (n + 255) / 256;     // must be <= 256

    // ---- D1: zero cursors + done ----
    const int zn = n * 16 + 16;
    zero_k<<<(zn + 255) / 256, 256, 0, stream>>>(curs, zn);

    // ---- D2: [scat1 (first) || cast+pack] ----
    const int prepBlocks = (n * 32 + 49152 + 255) / 256;
    scat1_prep_k<<<gE + prepBlocks, 256, 0, stream>>>(ei, curs, slot,
                                                      x, W0, W1, Wn, We,
                                                      xb, P0, P1, Pn, Pe, E, n, gE);

    // ---- D3: two-level scan (one dispatch) ----
    scanAB_k<<<NB, 256, 0, stream>>>(curs, rowe, bsum, boff, done, n, NB);

    // ---- D4: scat2 (standalone, full occupancy) ----
    scat2_k<<<gE, 256, 0, stream>>>(ei, rowe, boff, slot, colv, rowf, E, n);

    // ---- D5: [gemm0+att0 || proj_ego] ----
    gemm0_proj_k<<<2 * gN64, 256, 0, stream>>>(xb, P0, xlb, as0, ad0, a_s, a_d,
                                               Pe, be, out, n, gN64);

    // ---- D6: layer-0 aggregation ----
    agg_k<4><<<gWv, 256, 0, stream>>>(xlb, a_s, a_d, rowf, colv, b0, hb, n);

    // ---- D7: gemm1 + att1 ----
    gemm1_k<<<gN64, 256, 0, stream>>>(hb, P1, xlb, as1, ad1, a_s, a_d, n);

    // ---- D8: layer-1 aggregation ----
    agg_k<1><<<gWv, 256, 0, stream>>>(xlb, a_s, a_d, rowf, colv, b1, hb, n);

    // ---- D9: h_neighbor projection ----
    projN_k<<<gN64, 256, 0, stream>>>(hb, Pn, bn, out + (size_t)n * 64, n);
}